// Round 2
// baseline (1319.539 us; speedup 1.0000x reference)
//
#include <hip/hip_runtime.h>
#include <stdint.h>

#define ALPHA 1.702f
#define LIMIT 7.0f

constexpr int T_TOK = 512;
constexpr int HDIM  = 2880;
constexpr int IDIM  = 2880;
constexpr int NEXP  = 8;
constexpr int GUDIM = 2 * IDIM;   // 5760
constexpr int CAP   = 512;        // per-expert row capacity (worst case)
constexpr int KDIM  = 2880;       // contraction dim for both GEMMs

constexpr int BM = 256;
constexpr int BN = 64;
constexpr int BK = 32;
constexpr int RS = 34;            // LDS B row stride in shorts (17 dwords: gcd(17,32)=1 -> conflict-free)

typedef __attribute__((ext_vector_type(8))) short s16x8;
typedef __attribute__((ext_vector_type(4))) float f32x4;

__device__ __forceinline__ uint32_t pack2_bf16(float a, float b) {
  union { float f; uint32_t u; } x, y;
  x.f = a; y.f = b;
  uint32_t ra = (x.u + 0x7FFFu + ((x.u >> 16) & 1u)) >> 16;
  uint32_t rb = (y.u + 0x7FFFu + ((y.u >> 16) & 1u)) >> 16;
  return ra | (rb << 16);
}

__device__ __forceinline__ uint16_t f2bf(float f) {
  union { float f; uint32_t u; } x; x.f = f;
  return (uint16_t)((x.u + 0x7FFFu + ((x.u >> 16) & 1u)) >> 16);
}

// ---------------- routing: build per-expert token lists ----------------
__global__ void routing_kernel(const int* __restrict__ ridx,
                               const float* __restrict__ rw,
                               int* __restrict__ mcount,
                               int* __restrict__ tok,
                               float* __restrict__ comb) {
  __shared__ int cnt[NEXP];
  const int t = threadIdx.x;
  if (t < NEXP) cnt[t] = 0;
  __syncthreads();
  if (t < T_TOK) {
    const int i0 = ridx[t * 4 + 0], i1 = ridx[t * 4 + 1];
    const int i2 = ridx[t * 4 + 2], i3 = ridx[t * 4 + 3];
#pragma unroll
    for (int e = 0; e < NEXP; ++e) {
      int c = (i0 == e) + (i1 == e) + (i2 == e) + (i3 == e);
      if (c) {
        int p = atomicAdd(&cnt[e], 1);
        tok[e * CAP + p]  = t;
        comb[e * CAP + p] = rw[t * NEXP + e] * (float)c;
      }
    }
  }
  __syncthreads();
  if (t < NEXP) mcount[t] = cnt[t];
}

// ---------------- gather: x rows -> packed bf16 per expert ----------------
__global__ void gather_kernel(const float* __restrict__ x,
                              const int* __restrict__ mcount,
                              const int* __restrict__ tok,
                              uint32_t* __restrict__ Apack) {
  const int m = blockIdx.x;
  const int e = blockIdx.y;
  if (m >= mcount[e]) return;
  const int t = tok[e * CAP + m];
  const float* src = x + (size_t)t * HDIM;
  uint32_t* dst = Apack + (size_t)(e * CAP + m) * (HDIM / 2);
  for (int c = threadIdx.x * 4; c < HDIM; c += 1024) {
    float4 v = *(const float4*)(src + c);
    uint2 p = make_uint2(pack2_bf16(v.x, v.y), pack2_bf16(v.z, v.w));
    *(uint2*)(dst + c / 2) = p;
  }
}

// ---------------- fused expert GEMM, pipelined K-loop ----------------
// A: bf16 [NEXP][CAP][KDIM], fragments loaded straight from global (L2/L3-hot).
// B (W): fp32 [NEXP][KDIM][NDIM]; 2-deep register prefetch -> bf16 -> dbuf LDS.
// One raw barrier per K-iter; vmcnt loads stay in flight across it.
template <bool IS_GATEUP, int NDIM>
__global__ __launch_bounds__(512, 4) void moe_gemm(
    const uint16_t* __restrict__ A,
    const float* __restrict__ W,
    const float* __restrict__ bias,
    const int* __restrict__ mcount,
    const int* __restrict__ tok,
    const float* __restrict__ comb,
    uint16_t* __restrict__ Hout,
    float* __restrict__ yout)
{
  const int e = blockIdx.z;
  const int M = mcount[e];
  const int m_base = blockIdx.y * BM;
  if (m_base >= M) return;
  const int n_base = blockIdx.x * BN;

  __shared__ uint16_t lB[2][BN * RS];   // double-buffered, padded stride

  const int tid  = threadIdx.x;
  const int wid  = tid >> 6;
  const int lane = tid & 63;
  const int wm = wid >> 1;   // 0..3  (64 rows each)
  const int wn = wid & 1;    // 0..1  (32 cols each)

  f32x4 acc[4][2];
#pragma unroll
  for (int i = 0; i < 4; ++i)
#pragma unroll
    for (int j = 0; j < 2; ++j)
      acc[i][j] = f32x4{0.f, 0.f, 0.f, 0.f};

  // A fragment pointers (direct global): row = m_base+wm*64+mt*16+(lane&15), k0=(lane>>4)*8
  const uint16_t* aF0 = A + ((size_t)e * CAP + m_base + wm * 64 + (lane & 15)) * KDIM
                          + (lane >> 4) * 8;
  const uint16_t* aF1 = aF0 + (size_t)16 * KDIM;
  const uint16_t* aF2 = aF0 + (size_t)32 * KDIM;
  const uint16_t* aF3 = aF0 + (size_t)48 * KDIM;

  // B staging: thread -> (n = tid&63, k-quad = tid>>6); 4 fp32 strided rows
  const int bn  = tid & 63;
  const int bkq = tid >> 6;
  const int wOff = bn * RS + bkq * 4;                 // shorts (dword-aligned)
  const size_t wStep = (size_t)BK * NDIM;
  const float* wP0 = W + (size_t)e * KDIM * NDIM + (size_t)(bkq * 4) * NDIM + n_base + bn;

  const int bRd0 = (wn * 32 + (lane & 15)) * RS + (lane >> 4) * 8;  // shorts
  const int bRd1 = bRd0 + 16 * RS;

  constexpr int NK = KDIM / BK;  // 90

  // ---- preamble: B[0] -> regs -> LDS[0]; B[1] -> regs ----
  float p00, p01, p02, p03, p10, p11, p12, p13;
  p00 = wP0[0];
  p01 = wP0[(size_t)NDIM];
  p02 = wP0[2 * (size_t)NDIM];
  p03 = wP0[3 * (size_t)NDIM];
  {
    const float* w1 = wP0 + wStep;
    p10 = w1[0];
    p11 = w1[(size_t)NDIM];
    p12 = w1[2 * (size_t)NDIM];
    p13 = w1[3 * (size_t)NDIM];
  }
  const float* wP = wP0 + 2 * wStep;
  {
    uint32_t* wd = (uint32_t*)&lB[0][wOff];
    wd[0] = pack2_bf16(p00, p01);
    wd[1] = pack2_bf16(p02, p03);
  }
  __syncthreads();

  for (int kk = 0; kk < NK; kk += 2) {
#pragma unroll
    for (int u = 0; u < 2; ++u) {
      // 1) A fragments (issued first -> waitable without draining B prefetch)
      s16x8 af0 = *(const s16x8*)aF0;
      s16x8 af1 = *(const s16x8*)aF1;
      s16x8 af2 = *(const s16x8*)aF2;
      s16x8 af3 = *(const s16x8*)aF3;
      aF0 += BK; aF1 += BK; aF2 += BK; aF3 += BK;

      // 2) issue B[k+2] global loads (consumed 2 iterations from now)
      const int k = kk + u;
      const bool ld = (k + 2 < NK);
      const float* wq = ld ? wP : wP0;     // tail: dummy in-bounds loads
      float n0 = wq[0];
      float n1 = wq[(size_t)NDIM];
      float n2 = wq[2 * (size_t)NDIM];
      float n3 = wq[3 * (size_t)NDIM];
      if (ld) wP += wStep;

      // 3) LDS reads of B[k] fragments
      union { uint32_t w[4]; s16x8 v; } b0, b1;
      {
        const uint32_t* r0 = (const uint32_t*)&lB[u][bRd0];
        const uint32_t* r1 = (const uint32_t*)&lB[u][bRd1];
        b0.w[0] = r0[0]; b0.w[1] = r0[1]; b0.w[2] = r0[2]; b0.w[3] = r0[3];
        b1.w[0] = r1[0]; b1.w[1] = r1[1]; b1.w[2] = r1[2]; b1.w[3] = r1[3];
      }

      // 4) MFMA
      acc[0][0] = __builtin_amdgcn_mfma_f32_16x16x32_bf16(af0, b0.v, acc[0][0], 0, 0, 0);
      acc[0][1] = __builtin_amdgcn_mfma_f32_16x16x32_bf16(af0, b1.v, acc[0][1], 0, 0, 0);
      acc[1][0] = __builtin_amdgcn_mfma_f32_16x16x32_bf16(af1, b0.v, acc[1][0], 0, 0, 0);
      acc[1][1] = __builtin_amdgcn_mfma_f32_16x16x32_bf16(af1, b1.v, acc[1][1], 0, 0, 0);
      acc[2][0] = __builtin_amdgcn_mfma_f32_16x16x32_bf16(af2, b0.v, acc[2][0], 0, 0, 0);
      acc[2][1] = __builtin_amdgcn_mfma_f32_16x16x32_bf16(af2, b1.v, acc[2][1], 0, 0, 0);
      acc[3][0] = __builtin_amdgcn_mfma_f32_16x16x32_bf16(af3, b0.v, acc[3][0], 0, 0, 0);
      acc[3][1] = __builtin_amdgcn_mfma_f32_16x16x32_bf16(af3, b1.v, acc[3][1], 0, 0, 0);

      // 5) ds_write B[k+1] (loaded a full iteration ago) into the other buffer
      {
        uint32_t* wd = (uint32_t*)&lB[1 - u][wOff];
        if (u == 0) {
          wd[0] = pack2_bf16(p10, p11);
          wd[1] = pack2_bf16(p12, p13);
          p00 = n0; p01 = n1; p02 = n2; p03 = n3;
        } else {
          wd[0] = pack2_bf16(p00, p01);
          wd[1] = pack2_bf16(p02, p03);
          p10 = n0; p11 = n1; p12 = n2; p13 = n3;
        }
      }

      // 6) raw barrier: drain LDS only; B[k+2] global loads stay in flight
      asm volatile("s_waitcnt lgkmcnt(0)\n\ts_barrier" ::: "memory");
    }
  }

  // ---------------- epilogue ----------------
  const int col0 = n_base + wn * 32 + (lane & 15);   // C layout: col = lane&15
  const float b0 = bias[e * NDIM + col0];
  const float b1 = bias[e * NDIM + col0 + 16];

  if (IS_GATEUP) {
#pragma unroll
    for (int mt = 0; mt < 4; ++mt) {
      const int rbase = m_base + wm * 64 + mt * 16 + ((lane >> 4) << 2);
#pragma unroll
      for (int r = 0; r < 4; ++r) {
        float v0 = acc[mt][0][r] + b0;
        float v1 = acc[mt][1][r] + b1;
        float o0 = __shfl_xor(v0, 1, 64);
        float o1 = __shfl_xor(v1, 1, 64);
        int rr = rbase + r;
        if (rr < M && (lane & 1) == 0) {
          float g0 = fminf(v0, LIMIT);
          float u0 = fminf(fmaxf(o0, -LIMIT), LIMIT);
          float h0 = (u0 + 1.f) * (g0 / (1.f + __expf(-ALPHA * g0)));
          float g1 = fminf(v1, LIMIT);
          float u1 = fminf(fmaxf(o1, -LIMIT), LIMIT);
          float h1 = (u1 + 1.f) * (g1 / (1.f + __expf(-ALPHA * g1)));
          uint16_t* dst = Hout + ((size_t)e * CAP + rr) * IDIM;
          dst[col0 >> 1]        = f2bf(h0);
          dst[(col0 + 16) >> 1] = f2bf(h1);
        }
      }
    }
  } else {
#pragma unroll
    for (int mt = 0; mt < 4; ++mt) {
      const int rbase = m_base + wm * 64 + mt * 16 + ((lane >> 4) << 2);
#pragma unroll
      for (int r = 0; r < 4; ++r) {
        int rr = rbase + r;
        if (rr < M) {
          int t = tok[e * CAP + rr];
          float cw = comb[e * CAP + rr];
          float* yp = yout + (size_t)t * HDIM;
          atomicAdd(yp + col0,      cw * (acc[mt][0][r] + b0));
          atomicAdd(yp + col0 + 16, cw * (acc[mt][1][r] + b1));
        }
      }
    }
  }
}

extern "C" void kernel_launch(void* const* d_in, const int* in_sizes, int n_in,
                              void* d_out, int out_size, void* d_ws, size_t ws_size,
                              hipStream_t stream) {
  const float* x    = (const float*)d_in[0];
  const int*   ridx = (const int*)d_in[1];
  const float* rw   = (const float*)d_in[2];
  const float* w_gu = (const float*)d_in[3];
  const float* b_gu = (const float*)d_in[4];
  const float* w_dn = (const float*)d_in[5];
  const float* b_dn = (const float*)d_in[6];
  float* y = (float*)d_out;

  char* ws = (char*)d_ws;
  int*      mcount = (int*)ws;                                   // 8 ints
  int*      tok    = (int*)(ws + 256);                           // 8*512 ints
  float*    comb   = (float*)(ws + 256 + NEXP * CAP * 4);        // 8*512 floats
  uint16_t* Apack  = (uint16_t*)(ws + 256 + 2 * NEXP * CAP * 4); // 8*512*2880 bf16
  uint16_t* Hbuf   = Apack + (size_t)NEXP * CAP * KDIM;          // 8*512*2880 bf16

  hipMemsetAsync(y, 0, (size_t)T_TOK * HDIM * sizeof(float), stream);
  routing_kernel<<<1, 512, 0, stream>>>(ridx, rw, mcount, tok, comb);
  gather_kernel<<<dim3(CAP, NEXP), 256, 0, stream>>>(x, mcount, tok, (uint32_t*)Apack);
  moe_gemm<true, GUDIM><<<dim3(GUDIM / BN, 2, NEXP), 512, 0, stream>>>(
      Apack, w_gu, b_gu, mcount, tok, comb, Hbuf, y);
  moe_gemm<false, HDIM><<<dim3(HDIM / BN, 2, NEXP), 512, 0, stream>>>(
      Hbuf, w_dn, b_dn, mcount, tok, comb, (uint16_t*)nullptr, y);
}